// Round 5
// baseline (40.082 us; speedup 1.0000x reference)
//
#include <hip/hip_runtime.h>
#include <hip/hip_bf16.h>
#include <math.h>

#define D_MODEL 512
#define N_PEAKS 500
#define BATCH   1024
#define BLOCK   256
#define SPLIT   2
#define NPB     (N_PEAKS / SPLIT)   // 250 peaks per block
#define PAD     4                   // zero pad pairs so prefetch never branches

// out[b][2k]   = sum_n w[b,n] * sin(idx[b,n] * omega_k)
// out[b][2k+1] = sum_n w[b,n] * cos(idx[b,n] * omega_k)
// idx = ceil(loc*10), omega_k = exp(2k * -ln(10000)/512); reference pe row 0
// is zeroed -> mask idx==0 peaks at staging.
//
// R5: R4 showed the kernel is issue/latency-bound, not occupancy-bound
// (VGPR_Count=12 -> rolled loop; per-iter dependent ds_read->trans chain).
// This version software-pipelines explicitly: (idx,w) pairs are read from LDS
// as float4 (2 pairs) into registers TWO chunks ahead of use, so the ~100cyc
// LDS latency sits entirely under the previous chunks' trans work. 4
// independent accumulator chains give FMA ILP.
__global__ __launch_bounds__(BLOCK)
void SpectrumEncoding_84164179132426_kernel(const float* __restrict__ loc,
                                            const float* __restrict__ inten,
                                            float* __restrict__ out) {
    __shared__ __align__(16) float2 s_iw[NPB + PAD];  // {idxf, masked w}

    const int b    = blockIdx.x >> 1;
    const int half = blockIdx.x & 1;
    const int t    = threadIdx.x;

    const int base = b * N_PEAKS + half * NPB;
    if (t < NPB) {
        float l    = loc[base + t];
        float idxf = ceilf(l * 10.0f);     // matches jnp.ceil(loc*10)
        float w    = inten[base + t];
        s_iw[t] = make_float2(idxf, (idxf == 0.0f) ? 0.0f : w);
    } else if (t < NPB + PAD) {
        s_iw[t] = make_float2(0.0f, 0.0f); // pad: loaded by prefetch, never used
    }
    __syncthreads();

    // omega_k / (2*pi) in f64 once per thread (table-grade precision).
    const double cd = -log(10000.0) / (double)D_MODEL;
    const float wk = (float)(exp((double)(2 * t) * cd) / (2.0 * M_PI));

    float as0 = 0.f, ac0 = 0.f, as1 = 0.f, ac1 = 0.f;

    const float4* p = (const float4*)s_iw;   // 125 data chunks + 2 pad chunks

    float4 f0 = p[0];
    float4 f1 = p[1];

#define PROC(IDXF, W, AS, AC)                                   \
    {                                                           \
        const float rev = (IDXF) * wk;                          \
        const float r   = __builtin_amdgcn_fractf(rev);         \
        AS = fmaf((W), __builtin_amdgcn_sinf(r), AS);           \
        AC = fmaf((W), __builtin_amdgcn_cosf(r), AC);           \
    }

#pragma unroll 1
    for (int c = 0; c < NPB / 4; ++c) {      // 62.5 -> 125 float4s, 2 pairs each
        const float4 nf = p[c + 2];          // 2-deep prefetch (pad keeps it legal)
        PROC(f0.x, f0.y, as0, ac0);
        PROC(f0.z, f0.w, as1, ac1);
        f0 = f1;
        f1 = nf;
    }
    // NPB/4 = 62 full iterations processed chunks 0..61; finish 62..124.
    // (generic epilogue keeps correctness for any NPB%4; here NPB=250 ->
    //  125 chunks total, loop above does 62, epilogue does the rest)
    for (int c = NPB / 4; c < (NPB + 1) / 2; ++c) {
        PROC(f0.x, f0.y, as0, ac0);
        PROC(f0.z, f0.w, as1, ac1);
        f0 = f1;
        f1 = p[c + 2 < (NPB + PAD) / 2 ? c + 2 : 0];
    }
#undef PROC

    const float acc_s = as0 + as1;
    const float acc_c = ac0 + ac1;

    float* o = out + b * D_MODEL + 2 * t;
    unsafeAtomicAdd(o,     acc_s);           // 2 deterministic f32 addends
    unsafeAtomicAdd(o + 1, acc_c);
}

extern "C" void kernel_launch(void* const* d_in, const int* in_sizes, int n_in,
                              void* d_out, int out_size, void* d_ws, size_t ws_size,
                              hipStream_t stream) {
    const float* loc   = (const float*)d_in[0];   // [1024, 500] f32
    const float* inten = (const float*)d_in[1];   // [1024, 500] f32
    // d_in[2] (pe table) intentionally unused: recomputed analytically.
    float*       out   = (float*)d_out;           // [1024, 512] f32

    hipMemsetAsync(d_out, 0, (size_t)BATCH * D_MODEL * sizeof(float), stream);
    SpectrumEncoding_84164179132426_kernel<<<BATCH * SPLIT, BLOCK, 0, stream>>>(loc, inten, out);
}